// Round 14
// baseline (230.049 us; speedup 1.0000x reference)
//
#include <hip/hip_runtime.h>
#include <math.h>

#define NUM_K   1024
#define CDIM    64
#define HW      1024          // 32*32
#define NROWS   65536         // 64*1024
#define NBLK    1024          // epilogue blocks (64 rows each)
#define APAD    200           // A_s row stride in bf16 elems (400 B = 25*16B, odd -> bank-balanced)
#define EPS_THR 1.25e-4f      // candidate threshold on packed g~ (incl. pack granularity)
#define EPADR   68            // rescan LDS row pad (17 float4; r4-validated, 0 bank conflicts)

using bf16x8 = __attribute__((ext_vector_type(8))) short;
using f32x4  = __attribute__((ext_vector_type(4))) float;

#if __has_builtin(__builtin_amdgcn_fmed3f)
#define MED3F(a,b,c) __builtin_amdgcn_fmed3f((a),(b),(c))
#else
#define MED3F(a,b,c) fmaxf(fminf(fmaxf((a),(b)),(c)), fminf((a),(b)))
#endif

// numpy pairwise_sum order for n=64 contiguous fp32 (8 stride-8 chains,
// ((r0+r1)+(r2+r3))+((r4+r5)+(r6+r7))), squares rounded separately (no FMA).
__device__ __forceinline__ float np_sumsq64(const float* a) {
#pragma clang fp contract(off)
  float r0 = a[0]*a[0], r1 = a[1]*a[1], r2 = a[2]*a[2], r3 = a[3]*a[3];
  float r4 = a[4]*a[4], r5 = a[5]*a[5], r6 = a[6]*a[6], r7 = a[7]*a[7];
#pragma unroll
  for (int i = 8; i < 64; i += 8) {
    r0 += a[i+0]*a[i+0]; r1 += a[i+1]*a[i+1];
    r2 += a[i+2]*a[i+2]; r3 += a[i+3]*a[i+3];
    r4 += a[i+4]*a[i+4]; r5 += a[i+5]*a[i+5];
    r6 += a[i+6]*a[i+6]; r7 += a[i+7]*a[i+7];
  }
  return ((r0+r1)+(r2+r3))+((r4+r5)+(r6+r7));
}

// Pass 0 v4 (r14): wave-per-row fragment-major prep (validated r13, absmax 0)
// + block 0 zeroes counts/nflag (replaces two hipMemsetAsync dispatches;
// stream order guarantees completion before their consumers).
__global__ __launch_bounds__(256)
void vq_prep(const float* __restrict__ emb, float* __restrict__ norms,
             unsigned short* __restrict__ esp2,
             unsigned int* __restrict__ counts, unsigned int* __restrict__ nflag)
{
  if (blockIdx.x == 0) {
    for (int i = threadIdx.x; i < NUM_K; i += 256) counts[i] = 0;
    if (threadIdx.x == 0) *nflag = 0;
  }
  const int k    = (blockIdx.x * 256 + threadIdx.x) >> 6;   // wave id = code row
  const int lane = threadIdx.x & 63;                        // channel c
  if (k >= NUM_K) return;
  const float v = emb[k * CDIM + lane];
  const unsigned int hb = __float_as_uint(v) >> 16;         // bf16 trunc (hi)
  const float hf = __uint_as_float(hb << 16);
  const float res = v - hf;
  const unsigned int lb = __float_as_uint(res) >> 16;       // bf16 trunc (lo)

  const int cb = k >> 7, w = (k >> 5) & 3, ct = (k >> 4) & 1, l15 = k & 15;
  const unsigned fb = (unsigned)((cb * 4 + w) * 2 + ct) * 6u;   // fragment base /512
#pragma unroll
  for (int h = 0; h < 3; ++h) {             // split positions p = {c, 64+c, 128+c}
    const int p = h * 64 + lane;            // value: hi, hi, lo
    const unsigned short val = (unsigned short)(h == 2 ? lb : hb);
    const int s = p >> 5, g4p = (p >> 3) & 3, j = p & 7;
    esp2[(fb + (unsigned)s) * 512u + (unsigned)((g4p * 16 + l15) * 8 + j)] = val;
  }

  // norms[k] = np_sumsq64(emb row), bit-identical order.
  const float sq = v * v;                   // squares rounded separately
  float r = sq;
#pragma unroll
  for (int i = 1; i < 8; ++i)
    r += __shfl(sq, (lane & 7) + 8 * i, 64);   // lanes 0..7: left-assoc chains r_j
  float s = r + __shfl_xor(r, 1, 64);          // (r0+r1)
  s = s + __shfl_xor(s, 2, 64);                // (r0+r1)+(r2+r3)
  s = s + __shfl_xor(s, 4, 64);                // full pairwise bracket
  if (lane == 0) norms[k] = s;
}

// Pass 1: split-bf16 MFMA distance filter (math validated r1-r13, absmax 0).
// r14 changes: (a) __launch_bounds__(256,4) — VGPR 100 + 32 AGPR = 132 regs is
// 4 past the 128-reg cliff (3 -> 4 waves/SIMD); (b) flagged rows get out_idx
// sentinel -1 (epilogue merges pmin inline; vq_resfin dispatch deleted).
__global__ __launch_bounds__(256, 4)
void vq_dist(const float* __restrict__ xin, const float* __restrict__ norms,
             const unsigned short* __restrict__ esp2, float* __restrict__ out_idx,
             unsigned int* __restrict__ nflag, unsigned int* __restrict__ flaglist)
{
  __shared__ __align__(16) unsigned short A_s[64 * APAD];   // 25600 B
  __shared__ float red_m1[4][64];
  __shared__ float red_m2[4][64];

  const int t    = threadIdx.x;
  const int lane = t & 63;
  const int w    = t >> 6;        // wave id = 32-col slice of each 128-col chunk
  const int l15  = lane & 15;
  const int g4   = lane >> 4;

  const int n0  = blockIdx.x * 64;
  const int b   = n0 >> 10;
  const int hw0 = n0 & (HW - 1);

  // ---- stage A: load x (coalesced across rows), trunc-split, pack [hi|lo|hi] ----
  {
    const int r = t & 63, q = t >> 6;             // row, 16-channel quarter
    const float* xb = xin + (size_t)b * (CDIM * HW) + hw0 + r;
    unsigned short* arow = A_s + r * APAD;
#pragma unroll
    for (int u = 0; u < 8; ++u) {
      const int c0 = q * 16 + 2 * u;
      const float v0 = xb[(size_t)c0 * HW];
      const float v1 = xb[(size_t)(c0 + 1) * HW];
      const unsigned int h0 = __float_as_uint(v0) >> 16;
      const unsigned int h1 = __float_as_uint(v1) >> 16;
      const float r0 = v0 - __uint_as_float(h0 << 16);
      const float r1 = v1 - __uint_as_float(h1 << 16);
      const unsigned int lo0 = __float_as_uint(r0) >> 16;
      const unsigned int lo1 = __float_as_uint(r1) >> 16;
      const unsigned int hh = h0 | (h1 << 16);
      const unsigned int ll = lo0 | (lo1 << 16);
      *(unsigned int*)(arow + c0)        = hh;   // slots [0,64):   x_hi
      *(unsigned int*)(arow + 64 + c0)   = ll;   // slots [64,128): x_lo
      *(unsigned int*)(arow + 128 + c0)  = hh;   // slots [128,192):x_hi
    }
  }
  __syncthreads();

  float m1[16], m2[16];
#pragma unroll
  for (int i = 0; i < 16; ++i) { m1[i] = INFINITY; m2[i] = INFINITY; }

  // per-lane A fragment base (bf16 elems); rt adds 16*APAD, s adds 32
  const unsigned short* aF = A_s + l15 * APAD + g4 * 8;
  // fragment-major B: wave w's block; lane reads lane*16B (contiguous 1KB/wave).
  const unsigned short* pB = esp2 + (size_t)w * 6144 + (size_t)lane * 8;
  const float* pN = norms + w * 32 + l15;

#pragma unroll 1
  for (int cb = 0; cb < 8; ++cb) {
    const float nk0 = pN[0];
    const float nk1 = pN[16];

    bf16x8 bfr[6][2];
#pragma unroll
    for (int s = 0; s < 6; ++s) {
      bfr[s][0] = *(const bf16x8*)(pB + s * 512);          // contiguous 1KB wave read
      bfr[s][1] = *(const bf16x8*)(pB + 3072 + s * 512);
    }

    f32x4 acc[4][2];
#pragma unroll
    for (int rt = 0; rt < 4; ++rt)
#pragma unroll
      for (int ct = 0; ct < 2; ++ct)
        acc[rt][ct] = (f32x4){0.0f, 0.0f, 0.0f, 0.0f};

#pragma unroll
    for (int s = 0; s < 6; ++s) {
      const bf16x8 a0 = *(const bf16x8*)(aF + s * 32);
      const bf16x8 a1 = *(const bf16x8*)(aF + 16 * APAD + s * 32);
      const bf16x8 a2 = *(const bf16x8*)(aF + 32 * APAD + s * 32);
      const bf16x8 a3 = *(const bf16x8*)(aF + 48 * APAD + s * 32);
      acc[0][0] = __builtin_amdgcn_mfma_f32_16x16x32_bf16(a0, bfr[s][0], acc[0][0], 0, 0, 0);
      acc[1][0] = __builtin_amdgcn_mfma_f32_16x16x32_bf16(a1, bfr[s][0], acc[1][0], 0, 0, 0);
      acc[2][0] = __builtin_amdgcn_mfma_f32_16x16x32_bf16(a2, bfr[s][0], acc[2][0], 0, 0, 0);
      acc[3][0] = __builtin_amdgcn_mfma_f32_16x16x32_bf16(a3, bfr[s][0], acc[3][0], 0, 0, 0);
      acc[0][1] = __builtin_amdgcn_mfma_f32_16x16x32_bf16(a0, bfr[s][1], acc[0][1], 0, 0, 0);
      acc[1][1] = __builtin_amdgcn_mfma_f32_16x16x32_bf16(a1, bfr[s][1], acc[1][1], 0, 0, 0);
      acc[2][1] = __builtin_amdgcn_mfma_f32_16x16x32_bf16(a2, bfr[s][1], acc[2][1], 0, 0, 0);
      acc[3][1] = __builtin_amdgcn_mfma_f32_16x16x32_bf16(a3, bfr[s][1], acc[3][1], 0, 0, 0);
    }

    const unsigned kbase = (unsigned)(cb * 128 + w * 32 + l15);
    pB += 24576;
    pN += 128;

    // epilogue: g~ = nk - 2*dot~, pack col idx into low 10 mantissa bits,
    // batch ct-pair via med3 identity (bit-identical; validated r11-r13).
#pragma unroll
    for (int rt = 0; rt < 4; ++rt) {
#pragma unroll
      for (int rg = 0; rg < 4; ++rg) {
        const float g0 = fmaf(-2.0f, acc[rt][0][rg], nk0);
        const float g1 = fmaf(-2.0f, acc[rt][1][rg], nk1);
        const float p0 = __uint_as_float((__float_as_uint(g0) & 0xFFFFFC00u) | kbase);
        const float p1 = __uint_as_float((__float_as_uint(g1) & 0xFFFFFC00u) | (kbase + 16u));
        const float lo = fminf(p0, p1);
        const float hi = fmaxf(p0, p1);
        const int   si = rt * 4 + rg;
        m2[si] = fminf(m2[si], MED3F(m1[si], lo, hi));
        m1[si] = fminf(m1[si], lo);
      }
    }
  }

  // butterfly merge across the 16 col-lanes (packed: no index shuffles needed)
#pragma unroll
  for (int mask = 1; mask <= 8; mask <<= 1) {
#pragma unroll
    for (int si = 0; si < 16; ++si) {
      const float om1 = __shfl_xor(m1[si], mask, 64);
      const float om2 = __shfl_xor(m2[si], mask, 64);
      m2[si] = fminf(fminf(m2[si], om2), fmaxf(m1[si], om1));
      m1[si] = fminf(m1[si], om1);
    }
  }
  if (l15 == 0) {
#pragma unroll
    for (int rt = 0; rt < 4; ++rt)
#pragma unroll
      for (int rg = 0; rg < 4; ++rg) {
        const int row = rt * 16 + g4 * 4 + rg;
        red_m1[w][row] = m1[rt * 4 + rg];
        red_m2[w][row] = m2[rt * 4 + rg];
      }
  }
  __syncthreads();
  if (t < 64) {
    float M1 = red_m1[0][t], M2 = red_m2[0][t];
#pragma unroll
    for (int ww = 1; ww < 4; ++ww) {
      const float om1 = red_m1[ww][t], om2 = red_m2[ww][t];
      M2 = fminf(fminf(M2, om2), fmaxf(M1, om1));
      M1 = fminf(M1, om1);
    }
    const int K1 = (int)(__float_as_uint(M1) & 1023u);
    if (M2 - M1 <= EPS_THR) {        // gap too small -> exact rescan required
      out_idx[n0 + t] = -1.0f;       // sentinel: epilogue merges pmin inline
      const unsigned pos = atomicAdd(nflag, 1u);
      flaglist[pos] = (unsigned)(n0 + t);
    } else {
      out_idx[n0 + t] = (float)K1;   // provably exact fp32 argmin
    }
  }
}

// Pass 2b: exact rescan — r10's validated 2-D task split; r14: pmin indexed by
// ROW n (not flaglist position) so the epilogue can merge without resfin.
__global__ __launch_bounds__(256)
void vq_rescan(const float* __restrict__ xin, const float* __restrict__ emb,
               const float* __restrict__ norms,
               const unsigned int* __restrict__ nflag,
               const unsigned int* __restrict__ flaglist,
               unsigned long long* __restrict__ pmin)
{
  __shared__ __align__(16) float e_s[128 * EPADR];   // 34816 B
  __shared__ float x_s[16 * EPADR];                  // 4352 B
  const int t  = threadIdx.x;
  const int rr = t >> 4;    // row slot 0..15
  const int tk = t & 15;    // k-lane within row group
  const unsigned nf = *nflag;
  const unsigned T  = ((nf + 15) >> 4) * 8u;   // (row-group, chunk) tasks

  for (unsigned tau = blockIdx.x; tau < T; tau += gridDim.x) {
    const unsigned g  = tau >> 3;
    const int      cb = (int)(tau & 7);
    const unsigned ridx   = g * 16 + (unsigned)rr;
    const bool     active = ridx < nf;
    const int n  = (int)flaglist[active ? ridx : (nf - 1)];   // clamp: dummy row
    const int bb = n >> 10, hw = n & (HW - 1);

    __syncthreads();   // prior grid-stride iteration's readers done (rarely taken)

    // stage this row's x: 16 threads/row x 4 channels each
    {
      const float* xb = xin + (size_t)bb * (CDIM * HW) + hw;
#pragma unroll
      for (int j = 0; j < 4; ++j) {
        const int c = tk * 4 + j;
        x_s[rr * EPADR + c] = xb[(size_t)c * HW];
      }
    }
    // stage 128 codes of chunk cb: 2048 float4, 8/thread, coalesced
    {
      const float4* src = (const float4*)(emb + (size_t)cb * 128 * CDIM);
#pragma unroll
      for (int i = 0; i < 8; ++i) {
        const int f    = i * 256 + t;
        const int code = f >> 4, c4 = f & 15;
        *(float4*)(e_s + code * EPADR + c4 * 4) = src[f];
      }
    }
    __syncthreads();

    // per-thread register copy of its row
    float xr[CDIM];
#pragma unroll
    for (int c = 0; c < CDIM; ++c) xr[c] = x_s[rr * EPADR + c];
    const float S = np_sumsq64(xr);

    float dmin = INFINITY; int kmin = 0;
#pragma unroll 2
    for (int j = 0; j < 8; ++j) {
      const int kk = j * 16 + tk;
      const float* er = e_s + kk * EPADR;
      float d = 0.0f;
#pragma unroll
      for (int c4 = 0; c4 < 16; ++c4) {    // exact reference chain, c ascending
        const float4 a = *(const float4*)(er + 4 * c4);
        d = fmaf(xr[4*c4+0], a.x, d);
        d = fmaf(xr[4*c4+1], a.y, d);
        d = fmaf(xr[4*c4+2], a.z, d);
        d = fmaf(xr[4*c4+3], a.w, d);
      }
      const int k = cb * 128 + kk;
      const float q = (S - 2.0f * d) + norms[k];
      if (q < dmin) { dmin = q; kmin = k; }   // strict < keeps first (lowest k)
    }

    // lexicographic (d,k) first-min across the 16-lane row group
#pragma unroll
    for (int mask = 1; mask <= 8; mask <<= 1) {
      const float od = __shfl_xor(dmin, mask, 64);
      const int   ok = __shfl_xor(kmin, mask, 64);
      if (od < dmin || (od == dmin && ok < kmin)) { dmin = od; kmin = ok; }
    }
    if (active && tk == 0) {
      const float dc = dmin + 0.0f;              // -0.0 -> +0.0 canonicalization
      unsigned mb = __float_as_uint(dc);
      mb = (mb & 0x80000000u) ? ~mb : (mb | 0x80000000u);   // monotone total order
      pmin[(size_t)n * 8 + cb] =
          ((unsigned long long)mb << 32) | (unsigned long long)(unsigned)kmin;
    }
  }
}

// Pass 2a: epilogue for ALL rows — identical arithmetic & partials structure
// (validated r2-r13). r14: for sentinel rows (out_idx<0) merge the 8 pmin
// chunk-winners inline (u64 min = lex (d,k) first-min) and write out_idx.
__global__ __launch_bounds__(64)
void vq_epilogue(const float* __restrict__ xin, const float* __restrict__ emb,
                 float* __restrict__ out_idx, float* __restrict__ out0,
                 const unsigned long long* __restrict__ pmin,
                 double* __restrict__ partials, unsigned int* __restrict__ counts)
{
  __shared__ unsigned int hist_s[NUM_K];
  const int t = threadIdx.x;
  const int n = blockIdx.x * 64 + t;
  for (int i = t; i < NUM_K; i += 64) hist_s[i] = 0;
  __syncthreads();
  const int bb = n >> 10, hw = n & (HW - 1);
  const float* xb = xin + (size_t)bb * (CDIM * HW) + hw;
  int kmin = (int)out_idx[n];
  if (kmin < 0) {                             // flagged: merge rescan winners
    const unsigned long long* p = pmin + (size_t)n * 8;
    unsigned long long m = p[0];
#pragma unroll
    for (int j = 1; j < 8; ++j) { const unsigned long long v = p[j]; m = v < m ? v : m; }
    kmin = (int)(unsigned)(m & 1023u);
    out_idx[n] = (float)kmin;
  }
  atomicAdd(&hist_s[kmin], 1u);
  const float4* eb = (const float4*)(emb + (size_t)kmin * CDIM);
  float4* o = (float4*)(out0 + (size_t)n * CDIM);
  float ssq = 0.0f;
#pragma unroll
  for (int c4 = 0; c4 < 16; ++c4) {
    const float4 q4 = eb[c4];
    const float x0 = xb[(4*c4+0) * HW], x1 = xb[(4*c4+1) * HW];
    const float x2 = xb[(4*c4+2) * HW], x3 = xb[(4*c4+3) * HW];
    const float u0 = q4.x - x0, u1 = q4.y - x1, u2 = q4.z - x2, u3 = q4.w - x3;
    ssq = fmaf(u0, u0, fmaf(u1, u1, fmaf(u2, u2, fmaf(u3, u3, ssq))));
    o[c4] = make_float4(x0 + u0, x1 + u1, x2 + u2, x3 + u3);
  }
#pragma unroll
  for (int off = 32; off > 0; off >>= 1) ssq += __shfl_down(ssq, off, 64);
  if (t == 0) partials[blockIdx.x] = (double)ssq;   // deterministic, no FP atomics
  __syncthreads();
  for (int i = t; i < NUM_K; i += 64) {
    const unsigned int v = hist_s[i];
    if (v) atomicAdd(&counts[i], v);
  }
}

__global__ void vq_final(const double* __restrict__ partials,
                         const unsigned int* __restrict__ counts,
                         float* __restrict__ out_loss, float* __restrict__ out_perp)
{
  __shared__ double sh[256];
  const int t = threadIdx.x;
  double acc = 0.0, ent = 0.0;
  for (int i = t; i < NBLK; i += 256) acc += partials[i];
  for (int k = t; k < NUM_K; k += 256) {
    const double pr = (double)counts[k] * (1.0 / 65536.0);
    ent += pr * log(pr + 1e-10);
  }
  sh[t] = acc;
  __syncthreads();
  for (int s = 128; s > 0; s >>= 1) { if (t < s) sh[t] += sh[t + s]; __syncthreads(); }
  const double total = sh[0];
  __syncthreads();
  sh[t] = ent;
  __syncthreads();
  for (int s = 128; s > 0; s >>= 1) { if (t < s) sh[t] += sh[t + s]; __syncthreads(); }
  if (t == 0) {
    out_loss[0] = (float)(1.25 * total / 4194304.0);
    out_perp[0] = (float)exp(-sh[0]);
  }
}

extern "C" void kernel_launch(void* const* d_in, const int* in_sizes, int n_in,
                              void* d_out, int out_size, void* d_ws, size_t ws_size,
                              hipStream_t stream)
{
  const float* xin = (const float*)d_in[0];
  const float* emb = (const float*)d_in[1];
  float* out = (float*)d_out;

  // ws layout: [0,4K) fp32 norms[1024] | [4K,8K) u32 counts[1024] | [8K,16K) f64 partials[1024]
  float*        norms    = (float*)d_ws;
  unsigned int* counts   = (unsigned int*)((char*)d_ws + 4096);
  double*       partials = (double*)((char*)d_ws + 8192);

  float* out0     = out;                       // 4194304 elements (BHWC flat)
  float* out_loss = out + 4194304;             // scalar
  float* out_idx  = out + 4194305;             // 65536 elements (as float)
  float* out_perp = out + 4194305 + 65536;     // scalar

  // scratch stashed in out0 (consumed before vq_epilogue overwrites it):
  //   [0, 384K)           fragment-major split codebook esp2 (8*4*2*6 KB)
  //   [8M, 8M+4)          u32 flag counter
  //   [8M+4, 8M+4+256K)   u32 flaglist (worst case 65536 rows)
  //   [10M, 14M)          u64 pmin[65536][8] chunk-winners, indexed by ROW n
  //                       (only flagged rows' slots written & read)
  unsigned short*     esp2     = (unsigned short*)out0;
  unsigned int*       nflag    = (unsigned int*)((char*)out0 + (8u << 20));
  unsigned int*       flaglist = nflag + 1;
  unsigned long long* pmin     = (unsigned long long*)((char*)out0 + (10u << 20));

  vq_prep    <<<dim3(256),  dim3(256), 0, stream>>>(emb, norms, esp2, counts, nflag);
  vq_dist    <<<dim3(1024), dim3(256), 0, stream>>>(xin, norms, esp2, out_idx,
                                                    nflag, flaglist);
  vq_rescan  <<<dim3(2048), dim3(256), 0, stream>>>(xin, emb, norms, nflag,
                                                    flaglist, pmin);
  vq_epilogue<<<dim3(1024), dim3(64),  0, stream>>>(xin, emb, out_idx, out0, pmin,
                                                    partials, counts);
  vq_final   <<<dim3(1),    dim3(256), 0, stream>>>(partials, counts, out_loss, out_perp);
}

// Round 15
// 171.498 us; speedup vs baseline: 1.3414x; 1.3414x over previous
//
#include <hip/hip_runtime.h>
#include <math.h>

#define NUM_K   1024
#define CDIM    64
#define HW      1024          // 32*32
#define NROWS   65536         // 64*1024
#define NBLK    1024          // epilogue blocks (64 rows each)
#define APAD    200           // A_s row stride in bf16 elems (400 B = 25*16B, odd -> bank-balanced)
#define EPS_THR 1.25e-4f      // candidate threshold on packed g~ (incl. pack granularity)
#define EPADR   68            // rescan LDS row pad (17 float4; r4-validated, 0 bank conflicts)

using bf16x8 = __attribute__((ext_vector_type(8))) short;
using f32x4  = __attribute__((ext_vector_type(4))) float;

#if __has_builtin(__builtin_amdgcn_fmed3f)
#define MED3F(a,b,c) __builtin_amdgcn_fmed3f((a),(b),(c))
#else
#define MED3F(a,b,c) fmaxf(fminf(fmaxf((a),(b)),(c)), fminf((a),(b)))
#endif

// numpy pairwise_sum order for n=64 contiguous fp32 (8 stride-8 chains,
// ((r0+r1)+(r2+r3))+((r4+r5)+(r6+r7))), squares rounded separately (no FMA).
__device__ __forceinline__ float np_sumsq64(const float* a) {
#pragma clang fp contract(off)
  float r0 = a[0]*a[0], r1 = a[1]*a[1], r2 = a[2]*a[2], r3 = a[3]*a[3];
  float r4 = a[4]*a[4], r5 = a[5]*a[5], r6 = a[6]*a[6], r7 = a[7]*a[7];
#pragma unroll
  for (int i = 8; i < 64; i += 8) {
    r0 += a[i+0]*a[i+0]; r1 += a[i+1]*a[i+1];
    r2 += a[i+2]*a[i+2]; r3 += a[i+3]*a[i+3];
    r4 += a[i+4]*a[i+4]; r5 += a[i+5]*a[i+5];
    r6 += a[i+6]*a[i+6]; r7 += a[i+7]*a[i+7];
  }
  return ((r0+r1)+(r2+r3))+((r4+r5)+(r6+r7));
}

// Pass 0 v4: wave-per-row fragment-major prep (validated r13/r14, absmax 0)
// + block 0 zeroes counts/nflag (replaces two hipMemsetAsync dispatches).
__global__ __launch_bounds__(256)
void vq_prep(const float* __restrict__ emb, float* __restrict__ norms,
             unsigned short* __restrict__ esp2,
             unsigned int* __restrict__ counts, unsigned int* __restrict__ nflag)
{
  if (blockIdx.x == 0) {
    for (int i = threadIdx.x; i < NUM_K; i += 256) counts[i] = 0;
    if (threadIdx.x == 0) *nflag = 0;
  }
  const int k    = (blockIdx.x * 256 + threadIdx.x) >> 6;   // wave id = code row
  const int lane = threadIdx.x & 63;                        // channel c
  if (k >= NUM_K) return;
  const float v = emb[k * CDIM + lane];
  const unsigned int hb = __float_as_uint(v) >> 16;         // bf16 trunc (hi)
  const float hf = __uint_as_float(hb << 16);
  const float res = v - hf;
  const unsigned int lb = __float_as_uint(res) >> 16;       // bf16 trunc (lo)

  const int cb = k >> 7, w = (k >> 5) & 3, ct = (k >> 4) & 1, l15 = k & 15;
  const unsigned fb = (unsigned)((cb * 4 + w) * 2 + ct) * 6u;   // fragment base /512
#pragma unroll
  for (int h = 0; h < 3; ++h) {             // split positions p = {c, 64+c, 128+c}
    const int p = h * 64 + lane;            // value: hi, hi, lo
    const unsigned short val = (unsigned short)(h == 2 ? lb : hb);
    const int s = p >> 5, g4p = (p >> 3) & 3, j = p & 7;
    esp2[(fb + (unsigned)s) * 512u + (unsigned)((g4p * 16 + l15) * 8 + j)] = val;
  }

  // norms[k] = np_sumsq64(emb row), bit-identical order.
  const float sq = v * v;                   // squares rounded separately
  float r = sq;
#pragma unroll
  for (int i = 1; i < 8; ++i)
    r += __shfl(sq, (lane & 7) + 8 * i, 64);   // lanes 0..7: left-assoc chains r_j
  float s = r + __shfl_xor(r, 1, 64);          // (r0+r1)
  s = s + __shfl_xor(s, 2, 64);                // (r0+r1)+(r2+r3)
  s = s + __shfl_xor(s, 4, 64);                // full pairwise bracket
  if (lane == 0) norms[k] = s;
}

// Pass 1: split-bf16 MFMA distance filter (math validated r1-r14, absmax 0).
// r15: REVERT launch bounds to (256,2) — r14's (256,4) forced VGPR 100->64 and
// spilled ~60 regs to scratch (FETCH 9.8MB->247MB, dist 49->107us). 100 VGPR
// + 32 acc is ~130 live regs: between 3 waves/SIMD and spills there is no
// intermediate. Keeps r14's sentinel->epilogue-merge (resfin deleted).
__global__ __launch_bounds__(256, 2)
void vq_dist(const float* __restrict__ xin, const float* __restrict__ norms,
             const unsigned short* __restrict__ esp2, float* __restrict__ out_idx,
             unsigned int* __restrict__ nflag, unsigned int* __restrict__ flaglist)
{
  __shared__ __align__(16) unsigned short A_s[64 * APAD];   // 25600 B
  __shared__ float red_m1[4][64];
  __shared__ float red_m2[4][64];

  const int t    = threadIdx.x;
  const int lane = t & 63;
  const int w    = t >> 6;        // wave id = 32-col slice of each 128-col chunk
  const int l15  = lane & 15;
  const int g4   = lane >> 4;

  const int n0  = blockIdx.x * 64;
  const int b   = n0 >> 10;
  const int hw0 = n0 & (HW - 1);

  // ---- stage A: load x (coalesced across rows), trunc-split, pack [hi|lo|hi] ----
  {
    const int r = t & 63, q = t >> 6;             // row, 16-channel quarter
    const float* xb = xin + (size_t)b * (CDIM * HW) + hw0 + r;
    unsigned short* arow = A_s + r * APAD;
#pragma unroll
    for (int u = 0; u < 8; ++u) {
      const int c0 = q * 16 + 2 * u;
      const float v0 = xb[(size_t)c0 * HW];
      const float v1 = xb[(size_t)(c0 + 1) * HW];
      const unsigned int h0 = __float_as_uint(v0) >> 16;
      const unsigned int h1 = __float_as_uint(v1) >> 16;
      const float r0 = v0 - __uint_as_float(h0 << 16);
      const float r1 = v1 - __uint_as_float(h1 << 16);
      const unsigned int lo0 = __float_as_uint(r0) >> 16;
      const unsigned int lo1 = __float_as_uint(r1) >> 16;
      const unsigned int hh = h0 | (h1 << 16);
      const unsigned int ll = lo0 | (lo1 << 16);
      *(unsigned int*)(arow + c0)        = hh;   // slots [0,64):   x_hi
      *(unsigned int*)(arow + 64 + c0)   = ll;   // slots [64,128): x_lo
      *(unsigned int*)(arow + 128 + c0)  = hh;   // slots [128,192):x_hi
    }
  }
  __syncthreads();

  float m1[16], m2[16];
#pragma unroll
  for (int i = 0; i < 16; ++i) { m1[i] = INFINITY; m2[i] = INFINITY; }

  // per-lane A fragment base (bf16 elems); rt adds 16*APAD, s adds 32
  const unsigned short* aF = A_s + l15 * APAD + g4 * 8;
  // fragment-major B: wave w's block; lane reads lane*16B (contiguous 1KB/wave).
  const unsigned short* pB = esp2 + (size_t)w * 6144 + (size_t)lane * 8;
  const float* pN = norms + w * 32 + l15;

#pragma unroll 1
  for (int cb = 0; cb < 8; ++cb) {
    const float nk0 = pN[0];
    const float nk1 = pN[16];

    bf16x8 bfr[6][2];
#pragma unroll
    for (int s = 0; s < 6; ++s) {
      bfr[s][0] = *(const bf16x8*)(pB + s * 512);          // contiguous 1KB wave read
      bfr[s][1] = *(const bf16x8*)(pB + 3072 + s * 512);
    }

    f32x4 acc[4][2];
#pragma unroll
    for (int rt = 0; rt < 4; ++rt)
#pragma unroll
      for (int ct = 0; ct < 2; ++ct)
        acc[rt][ct] = (f32x4){0.0f, 0.0f, 0.0f, 0.0f};

#pragma unroll
    for (int s = 0; s < 6; ++s) {
      const bf16x8 a0 = *(const bf16x8*)(aF + s * 32);
      const bf16x8 a1 = *(const bf16x8*)(aF + 16 * APAD + s * 32);
      const bf16x8 a2 = *(const bf16x8*)(aF + 32 * APAD + s * 32);
      const bf16x8 a3 = *(const bf16x8*)(aF + 48 * APAD + s * 32);
      acc[0][0] = __builtin_amdgcn_mfma_f32_16x16x32_bf16(a0, bfr[s][0], acc[0][0], 0, 0, 0);
      acc[1][0] = __builtin_amdgcn_mfma_f32_16x16x32_bf16(a1, bfr[s][0], acc[1][0], 0, 0, 0);
      acc[2][0] = __builtin_amdgcn_mfma_f32_16x16x32_bf16(a2, bfr[s][0], acc[2][0], 0, 0, 0);
      acc[3][0] = __builtin_amdgcn_mfma_f32_16x16x32_bf16(a3, bfr[s][0], acc[3][0], 0, 0, 0);
      acc[0][1] = __builtin_amdgcn_mfma_f32_16x16x32_bf16(a0, bfr[s][1], acc[0][1], 0, 0, 0);
      acc[1][1] = __builtin_amdgcn_mfma_f32_16x16x32_bf16(a1, bfr[s][1], acc[1][1], 0, 0, 0);
      acc[2][1] = __builtin_amdgcn_mfma_f32_16x16x32_bf16(a2, bfr[s][1], acc[2][1], 0, 0, 0);
      acc[3][1] = __builtin_amdgcn_mfma_f32_16x16x32_bf16(a3, bfr[s][1], acc[3][1], 0, 0, 0);
    }

    const unsigned kbase = (unsigned)(cb * 128 + w * 32 + l15);
    pB += 24576;
    pN += 128;

    // epilogue: g~ = nk - 2*dot~, pack col idx into low 10 mantissa bits,
    // batch ct-pair via med3 identity (bit-identical; validated r11-r14).
#pragma unroll
    for (int rt = 0; rt < 4; ++rt) {
#pragma unroll
      for (int rg = 0; rg < 4; ++rg) {
        const float g0 = fmaf(-2.0f, acc[rt][0][rg], nk0);
        const float g1 = fmaf(-2.0f, acc[rt][1][rg], nk1);
        const float p0 = __uint_as_float((__float_as_uint(g0) & 0xFFFFFC00u) | kbase);
        const float p1 = __uint_as_float((__float_as_uint(g1) & 0xFFFFFC00u) | (kbase + 16u));
        const float lo = fminf(p0, p1);
        const float hi = fmaxf(p0, p1);
        const int   si = rt * 4 + rg;
        m2[si] = fminf(m2[si], MED3F(m1[si], lo, hi));
        m1[si] = fminf(m1[si], lo);
      }
    }
  }

  // butterfly merge across the 16 col-lanes (packed: no index shuffles needed)
#pragma unroll
  for (int mask = 1; mask <= 8; mask <<= 1) {
#pragma unroll
    for (int si = 0; si < 16; ++si) {
      const float om1 = __shfl_xor(m1[si], mask, 64);
      const float om2 = __shfl_xor(m2[si], mask, 64);
      m2[si] = fminf(fminf(m2[si], om2), fmaxf(m1[si], om1));
      m1[si] = fminf(m1[si], om1);
    }
  }
  if (l15 == 0) {
#pragma unroll
    for (int rt = 0; rt < 4; ++rt)
#pragma unroll
      for (int rg = 0; rg < 4; ++rg) {
        const int row = rt * 16 + g4 * 4 + rg;
        red_m1[w][row] = m1[rt * 4 + rg];
        red_m2[w][row] = m2[rt * 4 + rg];
      }
  }
  __syncthreads();
  if (t < 64) {
    float M1 = red_m1[0][t], M2 = red_m2[0][t];
#pragma unroll
    for (int ww = 1; ww < 4; ++ww) {
      const float om1 = red_m1[ww][t], om2 = red_m2[ww][t];
      M2 = fminf(fminf(M2, om2), fmaxf(M1, om1));
      M1 = fminf(M1, om1);
    }
    const int K1 = (int)(__float_as_uint(M1) & 1023u);
    if (M2 - M1 <= EPS_THR) {        // gap too small -> exact rescan required
      out_idx[n0 + t] = -1.0f;       // sentinel: epilogue merges pmin inline
      const unsigned pos = atomicAdd(nflag, 1u);
      flaglist[pos] = (unsigned)(n0 + t);
    } else {
      out_idx[n0 + t] = (float)K1;   // provably exact fp32 argmin
    }
  }
}

// Pass 2b: exact rescan — r10's validated 2-D task split; pmin indexed by ROW n.
__global__ __launch_bounds__(256)
void vq_rescan(const float* __restrict__ xin, const float* __restrict__ emb,
               const float* __restrict__ norms,
               const unsigned int* __restrict__ nflag,
               const unsigned int* __restrict__ flaglist,
               unsigned long long* __restrict__ pmin)
{
  __shared__ __align__(16) float e_s[128 * EPADR];   // 34816 B
  __shared__ float x_s[16 * EPADR];                  // 4352 B
  const int t  = threadIdx.x;
  const int rr = t >> 4;    // row slot 0..15
  const int tk = t & 15;    // k-lane within row group
  const unsigned nf = *nflag;
  const unsigned T  = ((nf + 15) >> 4) * 8u;   // (row-group, chunk) tasks

  for (unsigned tau = blockIdx.x; tau < T; tau += gridDim.x) {
    const unsigned g  = tau >> 3;
    const int      cb = (int)(tau & 7);
    const unsigned ridx   = g * 16 + (unsigned)rr;
    const bool     active = ridx < nf;
    const int n  = (int)flaglist[active ? ridx : (nf - 1)];   // clamp: dummy row
    const int bb = n >> 10, hw = n & (HW - 1);

    __syncthreads();   // prior grid-stride iteration's readers done (rarely taken)

    // stage this row's x: 16 threads/row x 4 channels each
    {
      const float* xb = xin + (size_t)bb * (CDIM * HW) + hw;
#pragma unroll
      for (int j = 0; j < 4; ++j) {
        const int c = tk * 4 + j;
        x_s[rr * EPADR + c] = xb[(size_t)c * HW];
      }
    }
    // stage 128 codes of chunk cb: 2048 float4, 8/thread, coalesced
    {
      const float4* src = (const float4*)(emb + (size_t)cb * 128 * CDIM);
#pragma unroll
      for (int i = 0; i < 8; ++i) {
        const int f    = i * 256 + t;
        const int code = f >> 4, c4 = f & 15;
        *(float4*)(e_s + code * EPADR + c4 * 4) = src[f];
      }
    }
    __syncthreads();

    // per-thread register copy of its row
    float xr[CDIM];
#pragma unroll
    for (int c = 0; c < CDIM; ++c) xr[c] = x_s[rr * EPADR + c];
    const float S = np_sumsq64(xr);

    float dmin = INFINITY; int kmin = 0;
#pragma unroll 2
    for (int j = 0; j < 8; ++j) {
      const int kk = j * 16 + tk;
      const float* er = e_s + kk * EPADR;
      float d = 0.0f;
#pragma unroll
      for (int c4 = 0; c4 < 16; ++c4) {    // exact reference chain, c ascending
        const float4 a = *(const float4*)(er + 4 * c4);
        d = fmaf(xr[4*c4+0], a.x, d);
        d = fmaf(xr[4*c4+1], a.y, d);
        d = fmaf(xr[4*c4+2], a.z, d);
        d = fmaf(xr[4*c4+3], a.w, d);
      }
      const int k = cb * 128 + kk;
      const float q = (S - 2.0f * d) + norms[k];
      if (q < dmin) { dmin = q; kmin = k; }   // strict < keeps first (lowest k)
    }

    // lexicographic (d,k) first-min across the 16-lane row group
#pragma unroll
    for (int mask = 1; mask <= 8; mask <<= 1) {
      const float od = __shfl_xor(dmin, mask, 64);
      const int   ok = __shfl_xor(kmin, mask, 64);
      if (od < dmin || (od == dmin && ok < kmin)) { dmin = od; kmin = ok; }
    }
    if (active && tk == 0) {
      const float dc = dmin + 0.0f;              // -0.0 -> +0.0 canonicalization
      unsigned mb = __float_as_uint(dc);
      mb = (mb & 0x80000000u) ? ~mb : (mb | 0x80000000u);   // monotone total order
      pmin[(size_t)n * 8 + cb] =
          ((unsigned long long)mb << 32) | (unsigned long long)(unsigned)kmin;
    }
  }
}

// Pass 2a: epilogue for ALL rows — identical arithmetic & partials structure
// (validated r2-r14). Sentinel rows (out_idx<0): merge 8 pmin winners inline.
__global__ __launch_bounds__(64)
void vq_epilogue(const float* __restrict__ xin, const float* __restrict__ emb,
                 float* __restrict__ out_idx, float* __restrict__ out0,
                 const unsigned long long* __restrict__ pmin,
                 double* __restrict__ partials, unsigned int* __restrict__ counts)
{
  __shared__ unsigned int hist_s[NUM_K];
  const int t = threadIdx.x;
  const int n = blockIdx.x * 64 + t;
  for (int i = t; i < NUM_K; i += 64) hist_s[i] = 0;
  __syncthreads();
  const int bb = n >> 10, hw = n & (HW - 1);
  const float* xb = xin + (size_t)bb * (CDIM * HW) + hw;
  int kmin = (int)out_idx[n];
  if (kmin < 0) {                             // flagged: merge rescan winners
    const unsigned long long* p = pmin + (size_t)n * 8;
    unsigned long long m = p[0];
#pragma unroll
    for (int j = 1; j < 8; ++j) { const unsigned long long v = p[j]; m = v < m ? v : m; }
    kmin = (int)(unsigned)(m & 1023u);
    out_idx[n] = (float)kmin;
  }
  atomicAdd(&hist_s[kmin], 1u);
  const float4* eb = (const float4*)(emb + (size_t)kmin * CDIM);
  float4* o = (float4*)(out0 + (size_t)n * CDIM);
  float ssq = 0.0f;
#pragma unroll
  for (int c4 = 0; c4 < 16; ++c4) {
    const float4 q4 = eb[c4];
    const float x0 = xb[(4*c4+0) * HW], x1 = xb[(4*c4+1) * HW];
    const float x2 = xb[(4*c4+2) * HW], x3 = xb[(4*c4+3) * HW];
    const float u0 = q4.x - x0, u1 = q4.y - x1, u2 = q4.z - x2, u3 = q4.w - x3;
    ssq = fmaf(u0, u0, fmaf(u1, u1, fmaf(u2, u2, fmaf(u3, u3, ssq))));
    o[c4] = make_float4(x0 + u0, x1 + u1, x2 + u2, x3 + u3);
  }
#pragma unroll
  for (int off = 32; off > 0; off >>= 1) ssq += __shfl_down(ssq, off, 64);
  if (t == 0) partials[blockIdx.x] = (double)ssq;   // deterministic, no FP atomics
  __syncthreads();
  for (int i = t; i < NUM_K; i += 64) {
    const unsigned int v = hist_s[i];
    if (v) atomicAdd(&counts[i], v);
  }
}

__global__ void vq_final(const double* __restrict__ partials,
                         const unsigned int* __restrict__ counts,
                         float* __restrict__ out_loss, float* __restrict__ out_perp)
{
  __shared__ double sh[256];
  const int t = threadIdx.x;
  double acc = 0.0, ent = 0.0;
  for (int i = t; i < NBLK; i += 256) acc += partials[i];
  for (int k = t; k < NUM_K; k += 256) {
    const double pr = (double)counts[k] * (1.0 / 65536.0);
    ent += pr * log(pr + 1e-10);
  }
  sh[t] = acc;
  __syncthreads();
  for (int s = 128; s > 0; s >>= 1) { if (t < s) sh[t] += sh[t + s]; __syncthreads(); }
  const double total = sh[0];
  __syncthreads();
  sh[t] = ent;
  __syncthreads();
  for (int s = 128; s > 0; s >>= 1) { if (t < s) sh[t] += sh[t + s]; __syncthreads(); }
  if (t == 0) {
    out_loss[0] = (float)(1.25 * total / 4194304.0);
    out_perp[0] = (float)exp(-sh[0]);
  }
}

extern "C" void kernel_launch(void* const* d_in, const int* in_sizes, int n_in,
                              void* d_out, int out_size, void* d_ws, size_t ws_size,
                              hipStream_t stream)
{
  const float* xin = (const float*)d_in[0];
  const float* emb = (const float*)d_in[1];
  float* out = (float*)d_out;

  // ws layout: [0,4K) fp32 norms[1024] | [4K,8K) u32 counts[1024] | [8K,16K) f64 partials[1024]
  float*        norms    = (float*)d_ws;
  unsigned int* counts   = (unsigned int*)((char*)d_ws + 4096);
  double*       partials = (double*)((char*)d_ws + 8192);

  float* out0     = out;                       // 4194304 elements (BHWC flat)
  float* out_loss = out + 4194304;             // scalar
  float* out_idx  = out + 4194305;             // 65536 elements (as float)
  float* out_perp = out + 4194305 + 65536;     // scalar

  // scratch stashed in out0 (consumed before vq_epilogue overwrites it):
  //   [0, 384K)           fragment-major split codebook esp2 (8*4*2*6 KB)
  //   [8M, 8M+4)          u32 flag counter
  //   [8M+4, 8M+4+256K)   u32 flaglist (worst case 65536 rows)
  //   [10M, 14M)          u64 pmin[65536][8] chunk-winners, indexed by ROW n
  unsigned short*     esp2     = (unsigned short*)out0;
  unsigned int*       nflag    = (unsigned int*)((char*)out0 + (8u << 20));
  unsigned int*       flaglist = nflag + 1;
  unsigned long long* pmin     = (unsigned long long*)((char*)out0 + (10u << 20));

  vq_prep    <<<dim3(256),  dim3(256), 0, stream>>>(emb, norms, esp2, counts, nflag);
  vq_dist    <<<dim3(1024), dim3(256), 0, stream>>>(xin, norms, esp2, out_idx,
                                                    nflag, flaglist);
  vq_rescan  <<<dim3(2048), dim3(256), 0, stream>>>(xin, emb, norms, nflag,
                                                    flaglist, pmin);
  vq_epilogue<<<dim3(1024), dim3(64),  0, stream>>>(xin, emb, out_idx, out0, pmin,
                                                    partials, counts);
  vq_final   <<<dim3(1),    dim3(256), 0, stream>>>(partials, counts, out_loss, out_perp);
}